// Round 12
// baseline (1366.746 us; speedup 1.0000x reference)
//
#include <hip/hip_runtime.h>

// Problem dims
#define B_   256
#define N_   16000
#define C_   32
#define K_   64
#define T_   124
#define NJ   125      // 128-sample half-window block sums, j = 0..124
#define HID_ 50
#define OUT_ 10

typedef unsigned int u32;

// Exact single f32 ops (prevent fma contraction / reassociation).
__device__ __forceinline__ float fadd(float a, float b) { return __fadd_rn(a, b); }
__device__ __forceinline__ float fmul(float a, float b) { return __fmul_rn(a, b); }
__device__ __forceinline__ float fsub(float a, float b) { return __fsub_rn(a, b); }
// Compile-time float4 component select (folds after unroll).
__device__ __forceinline__ float f4c(const float4& v, int i) {
    switch (i) { case 0: return v.x; case 1: return v.y; case 2: return v.z; default: return v.w; }
}

// ---------------------------------------------------------------------------
// Kernel A: conv (SAME pad_lo=31, correlation, sequential-k f32 FMA) + relu +
// numpy-pairwise 128-block sums -> Sg[b][c][j] (f32 global scratch).
//
// r10/r11 post-mortem: kreg[64] per thread can NOT be made register-resident
// reliably (64-VGPR pin -> remat (r9) or scratch spill (r10/r11: 683MB-3.5GB
// of scratch traffic)). Redesign: taps live in LDS (8 KB) and stream through
// a rolling 8-tap float4 window per channel (32 tap regs, short live range).
// Each wave processes 4 channels per audio read: one ds_read_b128 of audio
// feeds 4ch x 16 FMAs (audio LDS traffic /4). Per-output accumulation order
// (k ascending via q,e) is byte-identical to the passing rounds 8-11.
// Grid (B,16): one 1024-sample segment per block; wave w, group G in {0,1}
// owns channels w*8 + G*4 + {0..3}. LDS 29.7 KB -> 4 blocks/CU.
// ---------------------------------------------------------------------------
__global__ __launch_bounds__(256, 4) void convA(const float* __restrict__ audio,
                                                const float* __restrict__ gt,
                                                float* __restrict__ Sg) {
    __shared__ __align__(16) float abuf[1152];        //  4,608 B
    __shared__ __align__(16) float kLDS[C_ * K_];     //  8,192 B
    __shared__ __align__(16) float ybuf[4][4][264];   // 16,896 B [wave][ch][2blk*132]

    const int b = blockIdx.x, g = blockIdx.y;
    const int tid = threadIdx.x, w = tid >> 6, lane = tid & 63;
    const float* arow = audio + (size_t)b * N_;

    const int origin = (g << 10) - 32;
    for (int i = tid; i < 1152; i += 256) {
        int gi = origin + i;
        abuf[i] = (gi >= 0 && gi < N_) ? arow[gi] : 0.0f;
    }
    for (int i = tid; i < C_ * K_; i += 256) kLDS[i] = gt[i];
    __syncthreads();

    for (int G = 0; G < 2; ++G) {
        const float* kgrp = &kLDS[((w << 3) + (G << 2)) << 6];  // ch base row
        for (int pp = 0; pp < 4; ++pp) {
            const int Lb = (pp << 8) + (lane << 2);
            float y[4][4];
#pragma unroll
            for (int ch = 0; ch < 4; ++ch)
#pragma unroll
                for (int d = 0; d < 4; ++d) y[ch][d] = 0.0f;
            float4 Tp[4], Tc[4];
#pragma unroll
            for (int ch = 0; ch < 4; ++ch) Tp[ch] = make_float4(0.f, 0.f, 0.f, 0.f);

#pragma unroll
            for (int q = 0; q < 17; ++q) {
                float4 A4 = *(const float4*)(abuf + Lb + (q << 2));
                if (q < 16) {                       // q=16 uses only Tp
#pragma unroll
                    for (int ch = 0; ch < 4; ++ch)
                        Tc[ch] = *(const float4*)(kgrp + (ch << 6) + (q << 2));
                }
#pragma unroll
                for (int e = 0; e < 4; ++e) {
                    const float a = f4c(A4, e);
#pragma unroll
                    for (int ch = 0; ch < 4; ++ch) {
#pragma unroll
                        for (int d = 0; d < 4; ++d) {
                            const int kb = (q << 2) + e - 1 - d;   // compile-time
                            if (kb >= 0 && kb < K_) {
                                const int ts = e - 1 - d;          // tap window sel
                                const float tap = (ts >= 0) ? f4c(Tc[ch], ts)
                                                            : f4c(Tp[ch], 4 + ts);
                                y[ch][d] = fmaf(a, tap, y[ch][d]);
                            }
                        }
                    }
                }
#pragma unroll
                for (int ch = 0; ch < 4; ++ch) Tp[ch] = Tc[ch];
            }

            // relu + stash per-channel 256-sample slab (2 j-blocks)
#pragma unroll
            for (int ch = 0; ch < 4; ++ch) {
                float4 z;
                z.x = fmaxf(y[ch][0], 0.0f); z.y = fmaxf(y[ch][1], 0.0f);
                z.z = fmaxf(y[ch][2], 0.0f); z.w = fmaxf(y[ch][3], 0.0f);
                *(float4*)(&ybuf[w][ch][((lane >> 5) * 132) + ((lane & 31) << 2)]) = z;
            }
            // numpy pairwise-128: 64 lanes = 4ch x 2blk x 8slots.
            // r = seq sum of 16 stride-8 elems, then
            // ((r0+r1)+(r2+r3))+((r4+r5)+(r6+r7)) via commutative xor-shuffles
            {
                const int ch2 = lane >> 4, blk = (lane >> 3) & 1, j = lane & 7;
                const float* yb = &ybuf[w][ch2][blk * 132 + j];
                float r = yb[0];
#pragma unroll
                for (int m = 1; m < 16; ++m) r = fadd(r, yb[m << 3]);
                float v = fadd(r, __shfl_xor(r, 1));
                v = fadd(v, __shfl_xor(v, 2));
                v = fadd(v, __shfl_xor(v, 4));
                const int jg = (g << 3) + (pp << 1) + blk;
                const int c = (w << 3) + (G << 2) + ch2;
                if (j == 0 && jg < NJ) Sg[((size_t)b * C_ + c) * NJ + jg] = v;
            }
        }
    }
}

// ---------------------------------------------------------------------------
// Kernel B: SNN, fully parallel phases (r11's single-wave 124-step serial
// tail removed). Per-neuron membrane recurrences are independent across
// neurons -> run as 50/50/10 parallel chains; the two current matmuls are
// 6200/1240 independent sequential-g chains on 256 threads. Every f32 op
// sequence per value is byte-identical to the passing rounds.
// Grid 256 (one block per b), 256 threads. LDS ~137 KB, 1 block/CU.
// ---------------------------------------------------------------------------
__global__ __launch_bounds__(256, 1) void snnB(const float* __restrict__ Sg,
                                               const float* __restrict__ Wb,
                                               const float* __restrict__ Wic,
                                               const float* __restrict__ Wac,
                                               float* __restrict__ out) {
    __shared__ float sWb[HID_ * 321];      // 64,200 B (321%32==1: banks spread)
    __shared__ float sWic[HID_ * 51];      // 10,200 B
    __shared__ float sWac[OUT_ * 51];      //  2,040 B
    __shared__ u32   mask[T_ * 10];        //  4,960 B  (AN spike bits per step)
    __shared__ float cur[T_ * HID_];       // 24,800 B  (Bushy currents -> spkb)
    __shared__ float icur[T_ * HID_];      // 24,800 B  (IC currents -> spkic)
    __shared__ float acur[T_ * 12];        //  5,952 B  (AC currents, pad 12)

    const int b = blockIdx.x, tid = threadIdx.x;

    for (int i = tid; i < HID_ * 320; i += 256) {
        int r = i / 320;
        sWb[r * 321 + (i - r * 320)] = Wb[i];
    }
    for (int i = tid; i < HID_ * HID_; i += 256) {
        int r = i / 50;
        sWic[r * 51 + (i - r * 50)] = Wic[i];
    }
    for (int i = tid; i < OUT_ * HID_; i += 256) {
        int r = i / 50;
        sWac[r * 51 + (i - r * 50)] = Wac[i];
    }

    // ---- AN spike bitmasks: word (t, wd) covers i in [32wd, 32wd+32)
    const float* Sb = Sg + (size_t)b * C_ * NJ;
    for (int idx = tid; idx < T_ * 10; idx += 256) {
        int t = idx / 10, wd = idx - t * 10;
        u32 m = 0;
        int c_prev = -1;
        float env = 0.0f;
        for (int k = 0; k < 32; ++k) {
            int i = wd * 32 + k;
            int c = i / 10, s = i - c * 10;
            if (c != c_prev) {
                env = fmul(fadd(Sb[c * NJ + t], Sb[c * NJ + t + 1]), 0.00390625f);
                c_prev = c;
            }
            float sf = (s == 9) ? 1.5f : (float)(0.5 + (double)s * (1.0 / 9.0));
            if (fsub(fmul(env, sf), 0.5f) > 0.0f) m |= (1u << k);
        }
        mask[idx] = m;
    }
    __syncthreads();

    // ---- Bushy currents: 4 t-chains per weight-row pass (124 = 4*31)
    for (int k = tid; k < 31 * HID_; k += 256) {
        int t0 = k / 50, h = k - t0 * 50;
        const float* wr = sWb + h * 321;
        const u32* m0 = mask + (t0     ) * 10;
        const u32* m1 = mask + (t0 + 31) * 10;
        const u32* m2 = mask + (t0 + 62) * 10;
        const u32* m3 = mask + (t0 + 93) * 10;
        float a0 = 0.0f, a1 = 0.0f, a2 = 0.0f, a3 = 0.0f;
#pragma unroll 8
        for (int i = 0; i < 320; ++i) {
            float wv = wr[i];
            const int wi = i >> 5, sh = i & 31;
            a0 = fadd(a0, ((m0[wi] >> sh) & 1u) ? wv : 0.0f);
            a1 = fadd(a1, ((m1[wi] >> sh) & 1u) ? wv : 0.0f);
            a2 = fadd(a2, ((m2[wi] >> sh) & 1u) ? wv : 0.0f);
            a3 = fadd(a3, ((m3[wi] >> sh) & 1u) ? wv : 0.0f);
        }
        cur[(t0     ) * 50 + h] = a0;
        cur[(t0 + 31) * 50 + h] = a1;
        cur[(t0 + 62) * 50 + h] = a2;
        cur[(t0 + 93) * 50 + h] = a3;
    }
    __syncthreads();

    // ---- Bushy membrane chains: one thread per neuron, spikes in-place
    if (tid < HID_) {
        float mem = 0.0f;
        for (int t = 0; t < T_; ++t) {
            float m = fadd(fmul(0.95f, mem), cur[t * 50 + tid]);
            float sp = (fsub(m, 1.0f) > 0.0f) ? 1.0f : 0.0f;
            mem = fsub(m, sp);
            cur[t * 50 + tid] = sp;          // own slot only: race-free
        }
    }
    __syncthreads();

    // ---- IC currents: 6200 independent sequential-g chains
    for (int idx = tid; idx < T_ * HID_; idx += 256) {
        int t = idx / 50, h = idx - t * 50;
        const float* wr = sWic + h * 51;
        const float* sb = cur + t * 50;
        float acc = 0.0f;
#pragma unroll
        for (int g = 0; g < HID_; ++g) acc = fadd(acc, fmul(sb[g], wr[g]));
        icur[idx] = acc;
    }
    __syncthreads();

    // ---- IC membrane chains
    if (tid < HID_) {
        float mem = 0.0f;
        for (int t = 0; t < T_; ++t) {
            float m = fadd(fmul(0.95f, mem), icur[t * 50 + tid]);
            float sp = (fsub(m, 1.0f) > 0.0f) ? 1.0f : 0.0f;
            mem = fsub(m, sp);
            icur[t * 50 + tid] = sp;
        }
    }
    __syncthreads();

    // ---- AC currents: 1240 chains
    for (int idx = tid; idx < T_ * OUT_; idx += 256) {
        int t = idx / 10, o = idx - t * 10;
        const float* wr = sWac + o * 51;
        const float* sb = icur + t * 50;
        float acc = 0.0f;
#pragma unroll
        for (int g = 0; g < HID_; ++g) acc = fadd(acc, fmul(sb[g], wr[g]));
        acur[t * 12 + o] = acc;
    }
    __syncthreads();

    // ---- AC membrane chains + output stores
    if (tid < OUT_) {
        float mem = 0.0f;
        for (int t = 0; t < T_; ++t) {
            float m = fadd(fmul(0.95f, mem), acur[t * 12 + tid]);
            float sp = (fsub(m, 1.0f) > 0.0f) ? 1.0f : 0.0f;
            float mo = fsub(m, sp);
            mem = mo;
            size_t base = ((size_t)b * T_ + t) * OUT_ + tid;
            out[base] = sp;
            out[(size_t)(B_ * T_ * OUT_) + base] = mo;
        }
    }
}

// ---------------------------------------------------------------------------
extern "C" void kernel_launch(void* const* d_in, const int* in_sizes, int n_in,
                              void* d_out, int out_size, void* d_ws, size_t ws_size,
                              hipStream_t stream) {
    (void)in_sizes; (void)n_in; (void)out_size; (void)ws_size;
    const float* audio = (const float*)d_in[0];
    const float* gt    = (const float*)d_in[1];
    const float* Wb    = (const float*)d_in[2];
    const float* Wic   = (const float*)d_in[3];
    const float* Wac   = (const float*)d_in[4];

    float* Sg = (float*)d_ws;   // needs 256*32*125*4 = 4,096,000 B of ws

    convA<<<dim3(B_, 16), dim3(256), 0, stream>>>(audio, gt, Sg);
    snnB<<<dim3(B_), dim3(256), 0, stream>>>(Sg, Wb, Wic, Wac, (float*)d_out);
}

// Round 13
// 685.327 us; speedup vs baseline: 1.9943x; 1.9943x over previous
//
#include <hip/hip_runtime.h>

// Problem dims
#define B_   256
#define N_   16000
#define C_   32
#define K_   64
#define T_   124
#define NJ   125      // 128-sample half-window block sums, j = 0..124
#define HID_ 50
#define OUT_ 10

typedef unsigned int u32;

// Exact single f32 ops (prevent fma contraction / reassociation).
__device__ __forceinline__ float fadd(float a, float b) { return __fadd_rn(a, b); }
__device__ __forceinline__ float fmul(float a, float b) { return __fmul_rn(a, b); }
__device__ __forceinline__ float fsub(float a, float b) { return __fsub_rn(a, b); }
// Compile-time float4 component select (folds after unroll).
__device__ __forceinline__ float f4c(const float4& v, int i) {
    switch (i) { case 0: return v.x; case 1: return v.y; case 2: return v.z; default: return v.w; }
}

// ---------------------------------------------------------------------------
// Kernel A: conv (SAME pad_lo=31, correlation, sequential-k f32 FMA) + relu +
// numpy-pairwise 128-block sums -> Sg[b][c][j] (f32 global scratch).
//
// ROUND-13 FIX: __launch_bounds__(256, 2). Empirical law on this toolchain:
// 2nd arg 4 -> 64-VGPR cap (r9/r10/r12 all report VGPR_Count=64), arg 2 ->
// 128 (r11). The r12 rolling-window needs ~70-90 live VGPRs; at 64 it
// scratch-spilled (3.2 GB fetch / 1.7 GB write, 1150 us). At 128 it fits.
//
// Design (validated r12, absmax 0.0039): taps in LDS, rolling 8-tap float4
// window per channel; each wave processes 4 channels per audio ds_read_b128
// (one read feeds 64 FMAs). Per-output accumulation order (k ascending via
// q,e) is byte-identical to all passing rounds.
// Grid (B,16): one 1024-sample segment per block; wave w, group G in {0,1}
// owns channels w*8 + G*4 + {0..3}. LDS 29.7 KB.
// ---------------------------------------------------------------------------
__global__ __launch_bounds__(256, 2) void convA(const float* __restrict__ audio,
                                                const float* __restrict__ gt,
                                                float* __restrict__ Sg) {
    __shared__ __align__(16) float abuf[1152];        //  4,608 B
    __shared__ __align__(16) float kLDS[C_ * K_];     //  8,192 B
    __shared__ __align__(16) float ybuf[4][4][264];   // 16,896 B [wave][ch][2blk*132]

    const int b = blockIdx.x, g = blockIdx.y;
    const int tid = threadIdx.x, w = tid >> 6, lane = tid & 63;
    const float* arow = audio + (size_t)b * N_;

    const int origin = (g << 10) - 32;
    for (int i = tid; i < 1152; i += 256) {
        int gi = origin + i;
        abuf[i] = (gi >= 0 && gi < N_) ? arow[gi] : 0.0f;
    }
    for (int i = tid; i < C_ * K_; i += 256) kLDS[i] = gt[i];
    __syncthreads();

    for (int G = 0; G < 2; ++G) {
        const float* kgrp = &kLDS[((w << 3) + (G << 2)) << 6];  // ch base row
        for (int pp = 0; pp < 4; ++pp) {
            const int Lb = (pp << 8) + (lane << 2);
            float y[4][4];
#pragma unroll
            for (int ch = 0; ch < 4; ++ch)
#pragma unroll
                for (int d = 0; d < 4; ++d) y[ch][d] = 0.0f;
            float4 Tp[4], Tc[4];
#pragma unroll
            for (int ch = 0; ch < 4; ++ch) Tp[ch] = make_float4(0.f, 0.f, 0.f, 0.f);

#pragma unroll
            for (int q = 0; q < 17; ++q) {
                float4 A4 = *(const float4*)(abuf + Lb + (q << 2));
                if (q < 16) {                       // q=16 uses only Tp
#pragma unroll
                    for (int ch = 0; ch < 4; ++ch)
                        Tc[ch] = *(const float4*)(kgrp + (ch << 6) + (q << 2));
                }
#pragma unroll
                for (int e = 0; e < 4; ++e) {
                    const float a = f4c(A4, e);
#pragma unroll
                    for (int ch = 0; ch < 4; ++ch) {
#pragma unroll
                        for (int d = 0; d < 4; ++d) {
                            const int kb = (q << 2) + e - 1 - d;   // compile-time
                            if (kb >= 0 && kb < K_) {
                                const int ts = e - 1 - d;          // tap window sel
                                const float tap = (ts >= 0) ? f4c(Tc[ch], ts)
                                                            : f4c(Tp[ch], 4 + ts);
                                y[ch][d] = fmaf(a, tap, y[ch][d]);
                            }
                        }
                    }
                }
#pragma unroll
                for (int ch = 0; ch < 4; ++ch) Tp[ch] = Tc[ch];
            }

            // relu + stash per-channel 256-sample slab (2 j-blocks)
#pragma unroll
            for (int ch = 0; ch < 4; ++ch) {
                float4 z;
                z.x = fmaxf(y[ch][0], 0.0f); z.y = fmaxf(y[ch][1], 0.0f);
                z.z = fmaxf(y[ch][2], 0.0f); z.w = fmaxf(y[ch][3], 0.0f);
                *(float4*)(&ybuf[w][ch][((lane >> 5) * 132) + ((lane & 31) << 2)]) = z;
            }
            // numpy pairwise-128: 64 lanes = 4ch x 2blk x 8slots.
            // r = seq sum of 16 stride-8 elems, then
            // ((r0+r1)+(r2+r3))+((r4+r5)+(r6+r7)) via commutative xor-shuffles
            {
                const int ch2 = lane >> 4, blk = (lane >> 3) & 1, j = lane & 7;
                const float* yb = &ybuf[w][ch2][blk * 132 + j];
                float r = yb[0];
#pragma unroll
                for (int m = 1; m < 16; ++m) r = fadd(r, yb[m << 3]);
                float v = fadd(r, __shfl_xor(r, 1));
                v = fadd(v, __shfl_xor(v, 2));
                v = fadd(v, __shfl_xor(v, 4));
                const int jg = (g << 3) + (pp << 1) + blk;
                const int c = (w << 3) + (G << 2) + ch2;
                if (j == 0 && jg < NJ) Sg[((size_t)b * C_ + c) * NJ + jg] = v;
            }
        }
    }
}

// ---------------------------------------------------------------------------
// Kernel B: SNN, fully parallel phases (unchanged from round 12 — validated).
// AN bitmasks; Bushy currents 4 t-chains/row-pass; per-neuron membrane
// chains; IC/AC currents as independent sequential-g chains. Every f32 op
// sequence per value is byte-identical to the passing rounds.
// Grid 256 (one block per b), 256 threads. LDS ~137 KB, 1 block/CU.
// ---------------------------------------------------------------------------
__global__ __launch_bounds__(256, 1) void snnB(const float* __restrict__ Sg,
                                               const float* __restrict__ Wb,
                                               const float* __restrict__ Wic,
                                               const float* __restrict__ Wac,
                                               float* __restrict__ out) {
    __shared__ float sWb[HID_ * 321];      // 64,200 B (321%32==1: banks spread)
    __shared__ float sWic[HID_ * 51];      // 10,200 B
    __shared__ float sWac[OUT_ * 51];      //  2,040 B
    __shared__ u32   mask[T_ * 10];        //  4,960 B  (AN spike bits per step)
    __shared__ float cur[T_ * HID_];       // 24,800 B  (Bushy currents -> spkb)
    __shared__ float icur[T_ * HID_];      // 24,800 B  (IC currents -> spkic)
    __shared__ float acur[T_ * 12];        //  5,952 B  (AC currents, pad 12)

    const int b = blockIdx.x, tid = threadIdx.x;

    for (int i = tid; i < HID_ * 320; i += 256) {
        int r = i / 320;
        sWb[r * 321 + (i - r * 320)] = Wb[i];
    }
    for (int i = tid; i < HID_ * HID_; i += 256) {
        int r = i / 50;
        sWic[r * 51 + (i - r * 50)] = Wic[i];
    }
    for (int i = tid; i < OUT_ * HID_; i += 256) {
        int r = i / 50;
        sWac[r * 51 + (i - r * 50)] = Wac[i];
    }

    // ---- AN spike bitmasks: word (t, wd) covers i in [32wd, 32wd+32)
    const float* Sb = Sg + (size_t)b * C_ * NJ;
    for (int idx = tid; idx < T_ * 10; idx += 256) {
        int t = idx / 10, wd = idx - t * 10;
        u32 m = 0;
        int c_prev = -1;
        float env = 0.0f;
        for (int k = 0; k < 32; ++k) {
            int i = wd * 32 + k;
            int c = i / 10, s = i - c * 10;
            if (c != c_prev) {
                env = fmul(fadd(Sb[c * NJ + t], Sb[c * NJ + t + 1]), 0.00390625f);
                c_prev = c;
            }
            float sf = (s == 9) ? 1.5f : (float)(0.5 + (double)s * (1.0 / 9.0));
            if (fsub(fmul(env, sf), 0.5f) > 0.0f) m |= (1u << k);
        }
        mask[idx] = m;
    }
    __syncthreads();

    // ---- Bushy currents: 4 t-chains per weight-row pass (124 = 4*31)
    for (int k = tid; k < 31 * HID_; k += 256) {
        int t0 = k / 50, h = k - t0 * 50;
        const float* wr = sWb + h * 321;
        const u32* m0 = mask + (t0     ) * 10;
        const u32* m1 = mask + (t0 + 31) * 10;
        const u32* m2 = mask + (t0 + 62) * 10;
        const u32* m3 = mask + (t0 + 93) * 10;
        float a0 = 0.0f, a1 = 0.0f, a2 = 0.0f, a3 = 0.0f;
#pragma unroll 8
        for (int i = 0; i < 320; ++i) {
            float wv = wr[i];
            const int wi = i >> 5, sh = i & 31;
            a0 = fadd(a0, ((m0[wi] >> sh) & 1u) ? wv : 0.0f);
            a1 = fadd(a1, ((m1[wi] >> sh) & 1u) ? wv : 0.0f);
            a2 = fadd(a2, ((m2[wi] >> sh) & 1u) ? wv : 0.0f);
            a3 = fadd(a3, ((m3[wi] >> sh) & 1u) ? wv : 0.0f);
        }
        cur[(t0     ) * 50 + h] = a0;
        cur[(t0 + 31) * 50 + h] = a1;
        cur[(t0 + 62) * 50 + h] = a2;
        cur[(t0 + 93) * 50 + h] = a3;
    }
    __syncthreads();

    // ---- Bushy membrane chains: one thread per neuron, spikes in-place
    if (tid < HID_) {
        float mem = 0.0f;
        for (int t = 0; t < T_; ++t) {
            float m = fadd(fmul(0.95f, mem), cur[t * 50 + tid]);
            float sp = (fsub(m, 1.0f) > 0.0f) ? 1.0f : 0.0f;
            mem = fsub(m, sp);
            cur[t * 50 + tid] = sp;          // own slot only: race-free
        }
    }
    __syncthreads();

    // ---- IC currents: 6200 independent sequential-g chains
    for (int idx = tid; idx < T_ * HID_; idx += 256) {
        int t = idx / 50, h = idx - t * 50;
        const float* wr = sWic + h * 51;
        const float* sb = cur + t * 50;
        float acc = 0.0f;
#pragma unroll
        for (int g = 0; g < HID_; ++g) acc = fadd(acc, fmul(sb[g], wr[g]));
        icur[idx] = acc;
    }
    __syncthreads();

    // ---- IC membrane chains
    if (tid < HID_) {
        float mem = 0.0f;
        for (int t = 0; t < T_; ++t) {
            float m = fadd(fmul(0.95f, mem), icur[t * 50 + tid]);
            float sp = (fsub(m, 1.0f) > 0.0f) ? 1.0f : 0.0f;
            mem = fsub(m, sp);
            icur[t * 50 + tid] = sp;
        }
    }
    __syncthreads();

    // ---- AC currents: 1240 chains
    for (int idx = tid; idx < T_ * OUT_; idx += 256) {
        int t = idx / 10, o = idx - t * 10;
        const float* wr = sWac + o * 51;
        const float* sb = icur + t * 50;
        float acc = 0.0f;
#pragma unroll
        for (int g = 0; g < HID_; ++g) acc = fadd(acc, fmul(sb[g], wr[g]));
        acur[t * 12 + o] = acc;
    }
    __syncthreads();

    // ---- AC membrane chains + output stores
    if (tid < OUT_) {
        float mem = 0.0f;
        for (int t = 0; t < T_; ++t) {
            float m = fadd(fmul(0.95f, mem), acur[t * 12 + tid]);
            float sp = (fsub(m, 1.0f) > 0.0f) ? 1.0f : 0.0f;
            float mo = fsub(m, sp);
            mem = mo;
            size_t base = ((size_t)b * T_ + t) * OUT_ + tid;
            out[base] = sp;
            out[(size_t)(B_ * T_ * OUT_) + base] = mo;
        }
    }
}

// ---------------------------------------------------------------------------
extern "C" void kernel_launch(void* const* d_in, const int* in_sizes, int n_in,
                              void* d_out, int out_size, void* d_ws, size_t ws_size,
                              hipStream_t stream) {
    (void)in_sizes; (void)n_in; (void)out_size; (void)ws_size;
    const float* audio = (const float*)d_in[0];
    const float* gt    = (const float*)d_in[1];
    const float* Wb    = (const float*)d_in[2];
    const float* Wic   = (const float*)d_in[3];
    const float* Wac   = (const float*)d_in[4];

    float* Sg = (float*)d_ws;   // needs 256*32*125*4 = 4,096,000 B of ws

    convA<<<dim3(B_, 16), dim3(256), 0, stream>>>(audio, gt, Sg);
    snnB<<<dim3(B_), dim3(256), 0, stream>>>(Sg, Wb, Wic, Wac, (float*)d_out);
}

// Round 14
// 513.069 us; speedup vs baseline: 2.6639x; 1.3357x over previous
//
#include <hip/hip_runtime.h>

// Problem dims
#define B_   256
#define N_   16000
#define C_   32
#define K_   64
#define T_   124
#define NJ   125      // 128-sample half-window block sums, j = 0..124
#define HID_ 50
#define OUT_ 10

typedef unsigned int u32;

// Exact single f32 ops (prevent fma contraction / reassociation).
__device__ __forceinline__ float fadd(float a, float b) { return __fadd_rn(a, b); }
__device__ __forceinline__ float fmul(float a, float b) { return __fmul_rn(a, b); }
__device__ __forceinline__ float fsub(float a, float b) { return __fsub_rn(a, b); }
// Compile-time float4 component select (folds after unroll).
__device__ __forceinline__ float f4c(const float4& v, int i) {
    switch (i) { case 0: return v.x; case 1: return v.y; case 2: return v.z; default: return v.w; }
}

// ---------------------------------------------------------------------------
// Kernel A: conv (SAME pad_lo=31, correlation, sequential-k f32 FMA) + relu +
// numpy-pairwise 128-block sums -> Sg[b][c][j] (f32 global scratch).
//
// ROUND-14 FIX: r13 still spilled (615 MB scratch writes at VGPR=128).
// Root cause: the fully-unrolled q-loop lets the scheduler hoist/rename tap
// loads across all 17 iterations — scheduled live set >> 128. Structural
// fix: peel q=0 (kb>=0 guard) and q=16 (Tp-only), and keep q=1..15 as a
// REAL loop (#pragma unroll 1) whose body is boundary-free (kb always
// valid). Live set = one iteration (~70 regs): nothing left to spill.
// Per-output accumulation order (k ascending via q,e) unchanged: bit-exact.
//
// Grid (B,16): one 1024-sample segment per block; wave w, group G in {0,1}
// owns channels w*8 + G*4 + {0..3}. Each wave processes 4 channels per
// audio ds_read_b128 (one read feeds 64 FMAs). LDS 29.7 KB.
// ---------------------------------------------------------------------------
__global__ __launch_bounds__(256, 2) void convA(const float* __restrict__ audio,
                                                const float* __restrict__ gt,
                                                float* __restrict__ Sg) {
    __shared__ __align__(16) float abuf[1152];        //  4,608 B
    __shared__ __align__(16) float kLDS[C_ * K_];     //  8,192 B
    __shared__ __align__(16) float ybuf[4][4][264];   // 16,896 B [wave][ch][2blk*132]

    const int b = blockIdx.x, g = blockIdx.y;
    const int tid = threadIdx.x, w = tid >> 6, lane = tid & 63;
    const float* arow = audio + (size_t)b * N_;

    const int origin = (g << 10) - 32;
    for (int i = tid; i < 1152; i += 256) {
        int gi = origin + i;
        abuf[i] = (gi >= 0 && gi < N_) ? arow[gi] : 0.0f;
    }
    for (int i = tid; i < C_ * K_; i += 256) kLDS[i] = gt[i];
    __syncthreads();

    for (int G = 0; G < 2; ++G) {
        const float* kgrp = &kLDS[((w << 3) + (G << 2)) << 6];  // ch base row
        for (int pp = 0; pp < 4; ++pp) {
            const int Lb = (pp << 8) + (lane << 2);
            float y[4][4];
#pragma unroll
            for (int ch = 0; ch < 4; ++ch)
#pragma unroll
                for (int d = 0; d < 4; ++d) y[ch][d] = 0.0f;
            float4 Tp[4];

            // ---- q = 0 peel: kb = e-1-d, only kb>=0 terms (all from Tc)
            {
                float4 A4 = *(const float4*)(abuf + Lb);
                float4 Tc[4];
#pragma unroll
                for (int ch = 0; ch < 4; ++ch)
                    Tc[ch] = *(const float4*)(kgrp + (ch << 6));
#pragma unroll
                for (int e = 0; e < 4; ++e) {
                    const float a = f4c(A4, e);
#pragma unroll
                    for (int ch = 0; ch < 4; ++ch)
#pragma unroll
                        for (int d = 0; d < 4; ++d) {
                            const int kb = e - 1 - d;          // compile-time
                            if (kb >= 0)
                                y[ch][d] = fmaf(a, f4c(Tc[ch], kb), y[ch][d]);
                        }
                }
#pragma unroll
                for (int ch = 0; ch < 4; ++ch) Tp[ch] = Tc[ch];
            }

            // ---- q = 1..15: boundary-free, NOT unrolled (live set = 1 iter)
#pragma unroll 1
            for (int q = 1; q < 16; ++q) {
                float4 A4 = *(const float4*)(abuf + Lb + (q << 2));
                float4 Tc[4];
#pragma unroll
                for (int ch = 0; ch < 4; ++ch)
                    Tc[ch] = *(const float4*)(kgrp + (ch << 6) + (q << 2));
#pragma unroll
                for (int e = 0; e < 4; ++e) {
                    const float a = f4c(A4, e);
#pragma unroll
                    for (int ch = 0; ch < 4; ++ch)
#pragma unroll
                        for (int d = 0; d < 4; ++d) {
                            const int ts = e - 1 - d;          // compile-time
                            const float tap = (ts >= 0) ? f4c(Tc[ch], ts)
                                                        : f4c(Tp[ch], 4 + ts);
                            y[ch][d] = fmaf(a, tap, y[ch][d]);
                        }
                }
#pragma unroll
                for (int ch = 0; ch < 4; ++ch) Tp[ch] = Tc[ch];
            }

            // ---- q = 16 peel: kb = 64+e-1-d valid only for ts<0 (Tp terms)
            {
                float4 A4 = *(const float4*)(abuf + Lb + 64);
#pragma unroll
                for (int e = 0; e < 4; ++e) {
                    const float a = f4c(A4, e);
#pragma unroll
                    for (int ch = 0; ch < 4; ++ch)
#pragma unroll
                        for (int d = 0; d < 4; ++d) {
                            const int ts = e - 1 - d;          // compile-time
                            if (ts < 0)
                                y[ch][d] = fmaf(a, f4c(Tp[ch], 4 + ts), y[ch][d]);
                        }
                }
            }

            // relu + stash per-channel 256-sample slab (2 j-blocks)
#pragma unroll
            for (int ch = 0; ch < 4; ++ch) {
                float4 z;
                z.x = fmaxf(y[ch][0], 0.0f); z.y = fmaxf(y[ch][1], 0.0f);
                z.z = fmaxf(y[ch][2], 0.0f); z.w = fmaxf(y[ch][3], 0.0f);
                *(float4*)(&ybuf[w][ch][((lane >> 5) * 132) + ((lane & 31) << 2)]) = z;
            }
            // numpy pairwise-128: 64 lanes = 4ch x 2blk x 8slots.
            // r = seq sum of 16 stride-8 elems, then
            // ((r0+r1)+(r2+r3))+((r4+r5)+(r6+r7)) via commutative xor-shuffles
            {
                const int ch2 = lane >> 4, blk = (lane >> 3) & 1, j = lane & 7;
                const float* yb = &ybuf[w][ch2][blk * 132 + j];
                float r = yb[0];
#pragma unroll
                for (int m = 1; m < 16; ++m) r = fadd(r, yb[m << 3]);
                float v = fadd(r, __shfl_xor(r, 1));
                v = fadd(v, __shfl_xor(v, 2));
                v = fadd(v, __shfl_xor(v, 4));
                const int jg = (g << 3) + (pp << 1) + blk;
                const int c = (w << 3) + (G << 2) + ch2;
                if (j == 0 && jg < NJ) Sg[((size_t)b * C_ + c) * NJ + jg] = v;
            }
        }
    }
}

// ---------------------------------------------------------------------------
// Kernel B: SNN, fully parallel phases (unchanged from rounds 12/13).
// ---------------------------------------------------------------------------
__global__ __launch_bounds__(256, 1) void snnB(const float* __restrict__ Sg,
                                               const float* __restrict__ Wb,
                                               const float* __restrict__ Wic,
                                               const float* __restrict__ Wac,
                                               float* __restrict__ out) {
    __shared__ float sWb[HID_ * 321];      // 64,200 B (321%32==1: banks spread)
    __shared__ float sWic[HID_ * 51];      // 10,200 B
    __shared__ float sWac[OUT_ * 51];      //  2,040 B
    __shared__ u32   mask[T_ * 10];        //  4,960 B  (AN spike bits per step)
    __shared__ float cur[T_ * HID_];       // 24,800 B  (Bushy currents -> spkb)
    __shared__ float icur[T_ * HID_];      // 24,800 B  (IC currents -> spkic)
    __shared__ float acur[T_ * 12];        //  5,952 B  (AC currents, pad 12)

    const int b = blockIdx.x, tid = threadIdx.x;

    for (int i = tid; i < HID_ * 320; i += 256) {
        int r = i / 320;
        sWb[r * 321 + (i - r * 320)] = Wb[i];
    }
    for (int i = tid; i < HID_ * HID_; i += 256) {
        int r = i / 50;
        sWic[r * 51 + (i - r * 50)] = Wic[i];
    }
    for (int i = tid; i < OUT_ * HID_; i += 256) {
        int r = i / 50;
        sWac[r * 51 + (i - r * 50)] = Wac[i];
    }

    // ---- AN spike bitmasks: word (t, wd) covers i in [32wd, 32wd+32)
    const float* Sb = Sg + (size_t)b * C_ * NJ;
    for (int idx = tid; idx < T_ * 10; idx += 256) {
        int t = idx / 10, wd = idx - t * 10;
        u32 m = 0;
        int c_prev = -1;
        float env = 0.0f;
        for (int k = 0; k < 32; ++k) {
            int i = wd * 32 + k;
            int c = i / 10, s = i - c * 10;
            if (c != c_prev) {
                env = fmul(fadd(Sb[c * NJ + t], Sb[c * NJ + t + 1]), 0.00390625f);
                c_prev = c;
            }
            float sf = (s == 9) ? 1.5f : (float)(0.5 + (double)s * (1.0 / 9.0));
            if (fsub(fmul(env, sf), 0.5f) > 0.0f) m |= (1u << k);
        }
        mask[idx] = m;
    }
    __syncthreads();

    // ---- Bushy currents: 4 t-chains per weight-row pass (124 = 4*31)
    for (int k = tid; k < 31 * HID_; k += 256) {
        int t0 = k / 50, h = k - t0 * 50;
        const float* wr = sWb + h * 321;
        const u32* m0 = mask + (t0     ) * 10;
        const u32* m1 = mask + (t0 + 31) * 10;
        const u32* m2 = mask + (t0 + 62) * 10;
        const u32* m3 = mask + (t0 + 93) * 10;
        float a0 = 0.0f, a1 = 0.0f, a2 = 0.0f, a3 = 0.0f;
#pragma unroll 8
        for (int i = 0; i < 320; ++i) {
            float wv = wr[i];
            const int wi = i >> 5, sh = i & 31;
            a0 = fadd(a0, ((m0[wi] >> sh) & 1u) ? wv : 0.0f);
            a1 = fadd(a1, ((m1[wi] >> sh) & 1u) ? wv : 0.0f);
            a2 = fadd(a2, ((m2[wi] >> sh) & 1u) ? wv : 0.0f);
            a3 = fadd(a3, ((m3[wi] >> sh) & 1u) ? wv : 0.0f);
        }
        cur[(t0     ) * 50 + h] = a0;
        cur[(t0 + 31) * 50 + h] = a1;
        cur[(t0 + 62) * 50 + h] = a2;
        cur[(t0 + 93) * 50 + h] = a3;
    }
    __syncthreads();

    // ---- Bushy membrane chains: one thread per neuron, spikes in-place
    if (tid < HID_) {
        float mem = 0.0f;
        for (int t = 0; t < T_; ++t) {
            float m = fadd(fmul(0.95f, mem), cur[t * 50 + tid]);
            float sp = (fsub(m, 1.0f) > 0.0f) ? 1.0f : 0.0f;
            mem = fsub(m, sp);
            cur[t * 50 + tid] = sp;          // own slot only: race-free
        }
    }
    __syncthreads();

    // ---- IC currents: 6200 independent sequential-g chains
    for (int idx = tid; idx < T_ * HID_; idx += 256) {
        int t = idx / 50, h = idx - t * 50;
        const float* wr = sWic + h * 51;
        const float* sb = cur + t * 50;
        float acc = 0.0f;
#pragma unroll
        for (int g = 0; g < HID_; ++g) acc = fadd(acc, fmul(sb[g], wr[g]));
        icur[idx] = acc;
    }
    __syncthreads();

    // ---- IC membrane chains
    if (tid < HID_) {
        float mem = 0.0f;
        for (int t = 0; t < T_; ++t) {
            float m = fadd(fmul(0.95f, mem), icur[t * 50 + tid]);
            float sp = (fsub(m, 1.0f) > 0.0f) ? 1.0f : 0.0f;
            mem = fsub(m, sp);
            icur[t * 50 + tid] = sp;
        }
    }
    __syncthreads();

    // ---- AC currents: 1240 chains
    for (int idx = tid; idx < T_ * OUT_; idx += 256) {
        int t = idx / 10, o = idx - t * 10;
        const float* wr = sWac + o * 51;
        const float* sb = icur + t * 50;
        float acc = 0.0f;
#pragma unroll
        for (int g = 0; g < HID_; ++g) acc = fadd(acc, fmul(sb[g], wr[g]));
        acur[t * 12 + o] = acc;
    }
    __syncthreads();

    // ---- AC membrane chains + output stores
    if (tid < OUT_) {
        float mem = 0.0f;
        for (int t = 0; t < T_; ++t) {
            float m = fadd(fmul(0.95f, mem), acur[t * 12 + tid]);
            float sp = (fsub(m, 1.0f) > 0.0f) ? 1.0f : 0.0f;
            float mo = fsub(m, sp);
            mem = mo;
            size_t base = ((size_t)b * T_ + t) * OUT_ + tid;
            out[base] = sp;
            out[(size_t)(B_ * T_ * OUT_) + base] = mo;
        }
    }
}

// ---------------------------------------------------------------------------
extern "C" void kernel_launch(void* const* d_in, const int* in_sizes, int n_in,
                              void* d_out, int out_size, void* d_ws, size_t ws_size,
                              hipStream_t stream) {
    (void)in_sizes; (void)n_in; (void)out_size; (void)ws_size;
    const float* audio = (const float*)d_in[0];
    const float* gt    = (const float*)d_in[1];
    const float* Wb    = (const float*)d_in[2];
    const float* Wic   = (const float*)d_in[3];
    const float* Wac   = (const float*)d_in[4];

    float* Sg = (float*)d_ws;   // needs 256*32*125*4 = 4,096,000 B of ws

    convA<<<dim3(B_, 16), dim3(256), 0, stream>>>(audio, gt, Sg);
    snnB<<<dim3(B_), dim3(256), 0, stream>>>(Sg, Wb, Wic, Wac, (float*)d_out);
}